// Round 3
// baseline (289.812 us; speedup 1.0000x reference)
//
#include <hip/hip_runtime.h>

// QRNN fo-pooling, inference (zoneout = identity).
// Y: [T=512, B=32, 3H=3072] fp32 -> split F|Z|O along last dim.
// c_t = sigmoid(F)*c_{t-1} + (1-sigmoid(F))*tanh(Z); h_t = sigmoid(O)*c_t
// out: [T+1, B, H]; out[0] = init_h.

#define T_SEQ 512
#define BATCH 32
#define HID   1024
#define CH    (BATCH * HID)      // 32768 channels
#define ROWS  (BATCH * 3 * HID)  // 98304 floats per t-step of Y

__device__ __forceinline__ float fast_sigmoid(float x) {
    // 1 / (1 + 2^(-x*log2(e)))
    float e = __builtin_amdgcn_exp2f(-1.4426950408889634f * x);
    return __builtin_amdgcn_rcpf(1.0f + e);
}

__device__ __forceinline__ float fast_tanh(float x) {
    // 2*sigmoid(2x) - 1
    float e = __builtin_amdgcn_exp2f(-2.8853900817779268f * x);
    float s = __builtin_amdgcn_rcpf(1.0f + e);
    return __builtin_fmaf(2.0f, s, -1.0f);
}

__global__ __launch_bounds__(64) void fo_pool_kernel(
        const float* __restrict__ Y,
        const float* __restrict__ init_c,
        const float* __restrict__ init_h,
        float* __restrict__ out) {
    const int ch = blockIdx.x * 64 + threadIdx.x;   // [0, 32768)
    const int b  = ch >> 10;          // / HID
    const int h  = ch & (HID - 1);    // % HID
    const float* yb = Y + b * (3 * HID) + h;        // + t*ROWS; F at +0, Z at +HID, O at +2*HID

    // row 0 of output = init_h
    out[ch] = init_h[ch];
    float c = init_c[ch];

    constexpr int PF = 8;  // software-pipeline depth (t-steps per batch)
    float fA[PF], zA[PF], oA[PF];
    float fB[PF], zB[PF], oB[PF];

    auto LOAD = [&](float* f, float* z, float* o, int t0) {
#pragma unroll
        for (int i = 0; i < PF; ++i) {
            const float* p = yb + (t0 + i) * ROWS;
            f[i] = p[0];
            z[i] = p[HID];
            o[i] = p[2 * HID];
        }
    };
    auto COMP = [&](float* f, float* z, float* o, int t0) {
#pragma unroll
        for (int i = 0; i < PF; ++i) {
            float ff = fast_sigmoid(f[i]);
            float tz = fast_tanh(z[i]);
            float oo = fast_sigmoid(o[i]);
            c = ff * c + (1.0f - ff) * tz;
            out[(t0 + i + 1) * CH + ch] = c * oo;
        }
    };

    LOAD(fA, zA, oA, 0);
    for (int t0 = 0; t0 < T_SEQ; t0 += 2 * PF) {
        LOAD(fB, zB, oB, t0 + PF);          // prefetch next batch while A computes
        COMP(fA, zA, oA, t0);
        if (t0 + 2 * PF < T_SEQ) LOAD(fA, zA, oA, t0 + 2 * PF);
        COMP(fB, zB, oB, t0 + PF);
    }
}

extern "C" void kernel_launch(void* const* d_in, const int* in_sizes, int n_in,
                              void* d_out, int out_size, void* d_ws, size_t ws_size,
                              hipStream_t stream) {
    const float* Y      = (const float*)d_in[0];
    const float* init_c = (const float*)d_in[1];
    const float* init_h = (const float*)d_in[2];
    float* out = (float*)d_out;

    // 32768 channels, 1 thread each; 64-thread blocks -> 512 blocks (2 per CU)
    fo_pool_kernel<<<CH / 64, 64, 0, stream>>>(Y, init_c, init_h, out);
}